// Round 1
// baseline (89.049 us; speedup 1.0000x reference)
//
#include <hip/hip_runtime.h>
#include <cmath>

#define Bq 2
#define Sq 2048
#define Hq 16
#define Dq 64
#define CHUNK 64
#define NC (Sq / CHUNK)   // 32 chunks

// ---------------------------------------------------------------------------
// Kernel A: per-chunk KV outer-product sums.
// kv[((b*H+h)*NC + c)*4096 + dk*64 + dv] = sum_{s in chunk c} k[s][dk]*v[s][dv]
// ---------------------------------------------------------------------------
__global__ __launch_bounds__(256) void kv_chunk_kernel(
    const float* __restrict__ qk, const float* __restrict__ v,
    float* __restrict__ kv) {
  const int bid = blockIdx.x;
  const int c = bid & (NC - 1);
  const int h = (bid / NC) & (Hq - 1);
  const int b = bid / (NC * Hq);
  const int t0 = c * CHUNK;
  const int tid = threadIdx.x;
  __shared__ float kS[CHUNK][Dq];
  __shared__ float vS[CHUNK][Dq];
  for (int i = 0; i < 16; ++i) {
    int e = i * 256 + tid;
    int s = e >> 6, d = e & 63;
    size_t t = (size_t)(b * Sq + t0 + s);
    kS[s][d] = qk[((t * 2 + 1) * Hq + h) * Dq + d];   // k = qk[:,:,1]
    vS[s][d] = v[(t * Hq + h) * Dq + d];
  }
  __syncthreads();
  const int w = tid >> 6;     // wave id -> dk block [w*16, w*16+16)
  const int dv = tid & 63;
  float acc[16];
#pragma unroll
  for (int j = 0; j < 16; ++j) acc[j] = 0.f;
  for (int s = 0; s < CHUNK; ++s) {
    float vv = vS[s][dv];                          // stride-1, conflict-free
    const float4* krow = reinterpret_cast<const float4*>(&kS[s][w * 16]);
#pragma unroll
    for (int j4 = 0; j4 < 4; ++j4) {
      float4 k4 = krow[j4];                        // wave-uniform broadcast
      acc[j4 * 4 + 0] += k4.x * vv;
      acc[j4 * 4 + 1] += k4.y * vv;
      acc[j4 * 4 + 2] += k4.z * vv;
      acc[j4 * 4 + 3] += k4.w * vv;
    }
  }
  float* dst = kv + (((size_t)(b * Hq + h) * NC + c) << 12);
#pragma unroll
  for (int j = 0; j < 16; ++j) dst[(w * 16 + j) * 64 + dv] = acc[j];
}

// ---------------------------------------------------------------------------
// Kernel B: in-place exclusive prefix-sum over the NC chunks of each (b,h).
// One thread per (b,h,element); 32 serial steps, fully coalesced.
// ---------------------------------------------------------------------------
__global__ __launch_bounds__(256) void kv_scan_kernel(float* __restrict__ kv) {
  int g = blockIdx.x * 256 + threadIdx.x;   // 0 .. B*H*4096-1
  int bh = g >> 12;
  int e = g & 4095;
  float* p = kv + ((size_t)bh * NC << 12) + e;
  float run = 0.f;
#pragma unroll
  for (int c = 0; c < NC; ++c) {
    float x = p[(size_t)c << 12];
    p[(size_t)c << 12] = run;   // exclusive prefix (chunk 0 gets 0)
    run += x;
  }
}

// ---------------------------------------------------------------------------
// Kernel C: output.
//   out[t] = gate[t] * ( q[t] @ M_prev  +  sum_{s in chunk, s<=t} (q.k) v[s] )
// One block per (b,h,chunk); 4 waves; lane = dv (and = s for the k-row regs).
// ---------------------------------------------------------------------------
__global__ __launch_bounds__(256) void attn_out_kernel(
    const float* __restrict__ qk, const float* __restrict__ v,
    const float* __restrict__ nrm, const float* __restrict__ kv,
    float* __restrict__ out) {
  const int bid = blockIdx.x;
  const int c = bid & (NC - 1);
  const int h = (bid / NC) & (Hq - 1);
  const int b = bid / (NC * Hq);
  const int t0 = c * CHUNK;
  const int tid = threadIdx.x;
  const int w = tid >> 6;
  const int lane = tid & 63;
  __shared__ float qS[CHUNK][Dq];          // 16 KB
  __shared__ float vS[CHUNK][Dq];          // 16 KB
  __shared__ float sc[CHUNK][CHUNK + 1];   // +1 pad: bank-conflict-free
  __shared__ float gateS[CHUNK];

  for (int i = 0; i < 16; ++i) {
    int e = i * 256 + tid;
    int s = e >> 6, d = e & 63;
    size_t t = (size_t)(b * Sq + t0 + s);
    qS[s][d] = qk[((t * 2 + 0) * Hq + h) * Dq + d];   // q = qk[:,:,0]
    vS[s][d] = v[(t * Hq + h) * Dq + d];
  }
  if (tid < CHUNK)
    gateS[tid] = expf(-nrm[((size_t)(b * Sq) + t0 + tid) * Hq + h]);

  // k row (s = lane) into registers: 16 coalesced float4 loads
  float4 kreg[16];
  {
    const float4* kp = reinterpret_cast<const float4*>(
        qk + (((size_t)(b * Sq + t0 + lane) * 2 + 1) * Hq + h) * Dq);
#pragma unroll
    for (int j = 0; j < 16; ++j) kreg[j] = kp[j];
  }
  __syncthreads();

  // Phase A: scores sc[t][s], lower triangle only. t is wave-uniform.
  for (int i = 0; i < 16; ++i) {
    int t = i * 4 + w;
    const float4* qrow = reinterpret_cast<const float4*>(&qS[t][0]);
    float a = 0.f;
#pragma unroll
    for (int d4 = 0; d4 < 16; ++d4) {
      float4 q4 = qrow[d4];                // broadcast read (same addr/wave)
      a += q4.x * kreg[d4].x + q4.y * kreg[d4].y + q4.z * kreg[d4].z +
           q4.w * kreg[d4].w;
    }
    if (lane <= t) sc[t][lane] = a;
  }
  __syncthreads();

  // Phase B: column of M_prev (dv = lane) into registers; L2-resident reads.
  float Mcol[64];
  {
    const float* mb = kv + (((size_t)(b * Hq + h) * NC + c) << 12) + lane;
#pragma unroll
    for (int dk = 0; dk < 64; ++dk) Mcol[dk] = mb[dk * 64];  // coalesced
  }
  for (int i = 0; i < 16; ++i) {
    int t = i * 4 + w;                      // wave-uniform row
    const float4* qrow = reinterpret_cast<const float4*>(&qS[t][0]);
    float a = 0.f;
#pragma unroll
    for (int d4 = 0; d4 < 16; ++d4) {
      float4 q4 = qrow[d4];
      a += q4.x * Mcol[d4 * 4 + 0] + q4.y * Mcol[d4 * 4 + 1] +
           q4.z * Mcol[d4 * 4 + 2] + q4.w * Mcol[d4 * 4 + 3];
    }
    for (int s = 0; s <= t; ++s)            // wave-uniform trip count
      a += sc[t][s] * vS[s][lane];
    out[((size_t)(b * Sq + t0 + t) * Hq + h) * Dq + lane] = gateS[t] * a;
  }
}

extern "C" void kernel_launch(void* const* d_in, const int* in_sizes, int n_in,
                              void* d_out, int out_size, void* d_ws, size_t ws_size,
                              hipStream_t stream) {
  const float* qk = (const float*)d_in[0];
  const float* v  = (const float*)d_in[1];
  const float* nn = (const float*)d_in[2];
  float* out = (float*)d_out;
  float* kv  = (float*)d_ws;   // B*H*NC*64*64 floats = 16 MB

  kv_chunk_kernel<<<Bq * Hq * NC, 256, 0, stream>>>(qk, v, kv);
  kv_scan_kernel<<<(Bq * Hq * 4096) / 256, 256, 0, stream>>>(kv);
  attn_out_kernel<<<Bq * Hq * NC, 256, 0, stream>>>(qk, v, nn, kv, out);
}

// Round 2
// 57.870 us; speedup vs baseline: 1.5388x; 1.5388x over previous
//
#include <hip/hip_runtime.h>
#include <cmath>

#define Bq 2
#define Sq 2048
#define Hq 16
#define Dq 64
#define CHUNK 64
#define NC 32          // Sq / CHUNK
#define SP 72          // padded LDS row stride (elements): 144 B, 16B-aligned, 2-way max

typedef __attribute__((ext_vector_type(8))) short short8;  // 8 bf16 = 4 VGPRs
typedef __attribute__((ext_vector_type(4))) float f32x4;

__device__ inline short f2bf(float f) {           // RNE float->bf16 (raw bits)
  union { float f; unsigned u; } x{f};
  unsigned r = (x.u + 0x7FFFu + ((x.u >> 16) & 1u)) >> 16;
  return (short)r;
}

struct __align__(8) bf4 { short a, b, c, d; };

// ---------------------------------------------------------------------------
// Kernel A: per-chunk KV sums via MFMA.  kv[bh][c][dv][dk] = sum_s V[s][dv]K[s][dk]
//   = (V^T)(K^T)^T : X = Vt[dv][s], Y = Kt[dk][s]  (both staged transposed).
// ---------------------------------------------------------------------------
__global__ __launch_bounds__(256) void kv_chunk_kernel(
    const float* __restrict__ qk, const float* __restrict__ v,
    float* __restrict__ kv) {
  const int bid = blockIdx.x;
  const int c = bid & (NC - 1);
  const int h = (bid / NC) & (Hq - 1);
  const int b = bid / (NC * Hq);
  const int t0 = c * CHUNK;
  const int tid = threadIdx.x;
  __shared__ short ktS[64 * SP];
  __shared__ short vtS[64 * SP];

  const int sr = tid >> 4, c4 = tid & 15;
  for (int i = 0; i < 4; ++i) {
    const int rr = sr + 16 * i;
    const size_t t = (size_t)(b * Sq + t0 + rr);
    float4 k4 = *(const float4*)(qk + (((t * 2 + 1) * Hq + h) << 6) + c4 * 4);
    float4 v4 = *(const float4*)(v + ((t * Hq + h) << 6) + c4 * 4);
    ktS[(c4 * 4 + 0) * SP + rr] = f2bf(k4.x);
    ktS[(c4 * 4 + 1) * SP + rr] = f2bf(k4.y);
    ktS[(c4 * 4 + 2) * SP + rr] = f2bf(k4.z);
    ktS[(c4 * 4 + 3) * SP + rr] = f2bf(k4.w);
    vtS[(c4 * 4 + 0) * SP + rr] = f2bf(v4.x);
    vtS[(c4 * 4 + 1) * SP + rr] = f2bf(v4.y);
    vtS[(c4 * 4 + 2) * SP + rr] = f2bf(v4.z);
    vtS[(c4 * 4 + 3) * SP + rr] = f2bf(v4.w);
  }
  __syncthreads();

  const int w = tid >> 6, lane = tid & 63, g = lane >> 4, r16 = lane & 15;
  short8 vf[2];
#pragma unroll
  for (int kk = 0; kk < 2; ++kk)
    vf[kk] = *(const short8*)&vtS[(16 * w + r16) * SP + kk * 32 + 8 * g];

  float* dst = kv + (((size_t)((b * Hq + h) * NC + c)) << 12);
#pragma unroll
  for (int j = 0; j < 4; ++j) {
    f32x4 acc = {0.f, 0.f, 0.f, 0.f};
#pragma unroll
    for (int kk = 0; kk < 2; ++kk) {
      short8 kf = *(const short8*)&ktS[(16 * j + r16) * SP + kk * 32 + 8 * g];
      acc = __builtin_amdgcn_mfma_f32_16x16x32_bf16(vf[kk], kf, acc, 0, 0, 0);
    }
#pragma unroll
    for (int reg = 0; reg < 4; ++reg)
      dst[(16 * w + 4 * g + reg) * 64 + 16 * j + r16] = acc[reg];  // coalesced
  }
}

// ---------------------------------------------------------------------------
// Kernel B: in-place exclusive prefix over NC chunks per (b,h). fp32, coalesced.
// ---------------------------------------------------------------------------
__global__ __launch_bounds__(256) void kv_scan_kernel(float* __restrict__ kv) {
  int gi = blockIdx.x * 256 + threadIdx.x;
  int bh = gi >> 12;
  int e = gi & 4095;
  float* p = kv + ((size_t)bh * NC << 12) + e;
  float run = 0.f;
#pragma unroll
  for (int c = 0; c < NC; ++c) {
    float x = p[(size_t)c << 12];
    p[(size_t)c << 12] = run;
    run += x;
  }
}

// ---------------------------------------------------------------------------
// Kernel C: O = gate * ( mask(Q K^T) V + Q M_prev ), all three matmuls on MFMA.
// One block per (b,h,chunk); wave w owns output rows [16w,16w+16).
// ---------------------------------------------------------------------------
__global__ __launch_bounds__(256) void attn_out_kernel(
    const float* __restrict__ qk, const float* __restrict__ v,
    const float* __restrict__ nrm, const float* __restrict__ kv,
    float* __restrict__ out) {
  const int bid = blockIdx.x;
  const int c = bid & (NC - 1);
  const int h = (bid / NC) & (Hq - 1);
  const int b = bid / (NC * Hq);
  const int t0 = c * CHUNK;
  const int tid = threadIdx.x;
  __shared__ short qS[64 * SP];    // Q[t][d]
  __shared__ short kS[64 * SP];    // K[s][d]
  __shared__ short vtS[64 * SP];   // V^T[dv][s]
  __shared__ short mtS[64 * SP];   // M^T[dv][dk]  (kv ws already [dv][dk])
  __shared__ short smS[64 * SP];   // masked scores bf16 [t][s]
  __shared__ float gateS[64];

  const float* kvbase = kv + (((size_t)((b * Hq + h) * NC + c)) << 12);

  // ---- staging: 4 rows x 16 float4-cols per iteration --------------------
  const int sr = tid >> 4, c4 = tid & 15;
  for (int i = 0; i < 4; ++i) {
    const int rr = sr + 16 * i;
    const size_t t = (size_t)(b * Sq + t0 + rr);
    float4 q4 = *(const float4*)(qk + (((t * 2 + 0) * Hq + h) << 6) + c4 * 4);
    float4 k4 = *(const float4*)(qk + (((t * 2 + 1) * Hq + h) << 6) + c4 * 4);
    float4 v4 = *(const float4*)(v + ((t * Hq + h) << 6) + c4 * 4);
    float4 m4 = *(const float4*)(kvbase + rr * 64 + c4 * 4);
    bf4 qb = {f2bf(q4.x), f2bf(q4.y), f2bf(q4.z), f2bf(q4.w)};
    bf4 kb = {f2bf(k4.x), f2bf(k4.y), f2bf(k4.z), f2bf(k4.w)};
    bf4 mb = {f2bf(m4.x), f2bf(m4.y), f2bf(m4.z), f2bf(m4.w)};
    *(bf4*)&qS[rr * SP + c4 * 4] = qb;
    *(bf4*)&kS[rr * SP + c4 * 4] = kb;
    *(bf4*)&mtS[rr * SP + c4 * 4] = mb;
    vtS[(c4 * 4 + 0) * SP + rr] = f2bf(v4.x);   // transpose-scatter (one-time)
    vtS[(c4 * 4 + 1) * SP + rr] = f2bf(v4.y);
    vtS[(c4 * 4 + 2) * SP + rr] = f2bf(v4.z);
    vtS[(c4 * 4 + 3) * SP + rr] = f2bf(v4.w);
  }
  if (tid < 64)
    gateS[tid] = __expf(-nrm[((size_t)(b * Sq) + t0 + tid) * Hq + h]);
  __syncthreads();

  const int w = tid >> 6, lane = tid & 63, g = lane >> 4, r16 = lane & 15;

  // Q fragments for this wave's row slab (reused by Q@M)
  short8 qf[2];
#pragma unroll
  for (int kk = 0; kk < 2; ++kk)
    qf[kk] = *(const short8*)&qS[(16 * w + r16) * SP + kk * 32 + 8 * g];

  // ---- S = Q K^T, masked, -> smS (only tiles j<=w can be nonzero) --------
  for (int j = 0; j <= w; ++j) {
    f32x4 acc = {0.f, 0.f, 0.f, 0.f};
#pragma unroll
    for (int kk = 0; kk < 2; ++kk) {
      short8 kf = *(const short8*)&kS[(16 * j + r16) * SP + kk * 32 + 8 * g];
      acc = __builtin_amdgcn_mfma_f32_16x16x32_bf16(qf[kk], kf, acc, 0, 0, 0);
    }
    const int scol = 16 * j + r16;
#pragma unroll
    for (int reg = 0; reg < 4; ++reg) {
      const int trow = 16 * w + 4 * g + reg;
      smS[trow * SP + scol] = (scol <= trow) ? f2bf(acc[reg]) : (short)0;
    }
  }
  for (int j = w + 1; j < 4; ++j) {
    const int scol = 16 * j + r16;
#pragma unroll
    for (int reg = 0; reg < 4; ++reg)
      smS[(16 * w + 4 * g + reg) * SP + scol] = 0;
  }
  __syncthreads();

  // ---- O = Sm V + Q M, gate, store ---------------------------------------
  const int nk = (w < 2) ? 1 : 2;   // wave-uniform: s<=t limits live s-tiles
  short8 sf[2];
  for (int kk = 0; kk < nk; ++kk)
    sf[kk] = *(const short8*)&smS[(16 * w + r16) * SP + kk * 32 + 8 * g];
  float gr[4];
#pragma unroll
  for (int reg = 0; reg < 4; ++reg)
    gr[reg] = gateS[16 * w + 4 * g + reg];

#pragma unroll
  for (int j = 0; j < 4; ++j) {     // dv tiles
    f32x4 acc = {0.f, 0.f, 0.f, 0.f};
    for (int kk = 0; kk < nk; ++kk) {
      short8 vfr = *(const short8*)&vtS[(16 * j + r16) * SP + kk * 32 + 8 * g];
      acc = __builtin_amdgcn_mfma_f32_16x16x32_bf16(sf[kk], vfr, acc, 0, 0, 0);
    }
#pragma unroll
    for (int kk = 0; kk < 2; ++kk) {
      short8 mfr = *(const short8*)&mtS[(16 * j + r16) * SP + kk * 32 + 8 * g];
      acc = __builtin_amdgcn_mfma_f32_16x16x32_bf16(qf[kk], mfr, acc, 0, 0, 0);
    }
    const int dv = 16 * j + r16;
#pragma unroll
    for (int reg = 0; reg < 4; ++reg) {
      const int trow = 16 * w + 4 * g + reg;
      out[((size_t)(b * Sq + t0 + trow) * Hq + h) * Dq + dv] = gr[reg] * acc[reg];
    }
  }
}

extern "C" void kernel_launch(void* const* d_in, const int* in_sizes, int n_in,
                              void* d_out, int out_size, void* d_ws, size_t ws_size,
                              hipStream_t stream) {
  const float* qk = (const float*)d_in[0];
  const float* v  = (const float*)d_in[1];
  const float* nn = (const float*)d_in[2];
  float* out = (float*)d_out;
  float* kv  = (float*)d_ws;   // B*H*NC*64*64 fp32 = 16 MB

  kv_chunk_kernel<<<Bq * Hq * NC, 256, 0, stream>>>(qk, v, kv);
  kv_scan_kernel<<<(Bq * Hq * 4096) / 256, 256, 0, stream>>>(kv);
  attn_out_kernel<<<Bq * Hq * NC, 256, 0, stream>>>(qk, v, nn, kv, out);
}

// Round 3
// 53.390 us; speedup vs baseline: 1.6679x; 1.0839x over previous
//
#include <hip/hip_runtime.h>
#include <hip/hip_bf16.h>
#include <cmath>

#define Bq 2
#define Sq 2048
#define Hq 16
#define CHUNK 64
#define NC 32

typedef __attribute__((ext_vector_type(8))) short short8;  // 8 bf16
typedef __attribute__((ext_vector_type(4))) float f32x4;
typedef unsigned short ushort_t;
typedef unsigned int uint_t;

__device__ inline short f2b(float f) {
  __hip_bfloat16 h = __float2bfloat16(f);   // RNE, single v_cvt on gfx950
  return *reinterpret_cast<short*>(&h);
}

// XOR-swizzled element index for a 64x64 bf16 tile (128B rows, 16B slots):
// kills bank conflicts for b128 reads of 16 rows at a fixed column block.
__device__ inline int swz(int row, int col) {
  return (row << 6) + ((((col >> 3) ^ (row & 7))) << 3) + (col & 7);
}

// ---------------------------------------------------------------------------
// Kernel A: per-chunk KV sums (bf16 out).  kvw[bh][c][dv][dk] = sum_s V[s][dv]K[s][dk]
// Staged transposed via coalesced global column reads + swizzled b128 writes.
// ---------------------------------------------------------------------------
__global__ __launch_bounds__(256) void kv_chunk_kernel(
    const float* __restrict__ qk, const float* __restrict__ v,
    ushort_t* __restrict__ kvw) {
  const int bid = blockIdx.x;
  const int c = bid & (NC - 1), h = (bid / NC) & (Hq - 1), b = bid / (NC * Hq);
  const int t0 = c * CHUNK;
  const int tid = threadIdx.x;
  __shared__ short ktS[4096];   // K^T[dk][s]
  __shared__ short vtS[4096];   // V^T[dv][s]

  const int x = tid & 63, seg = tid >> 6;
  for (int e = 0; e < 2; ++e) {
    const int s0 = seg * 16 + e * 8;
    short8 kb, vb;
#pragma unroll
    for (int j = 0; j < 8; ++j) {
      const size_t t = (size_t)(b * Sq + t0 + s0 + j);
      kb[j] = f2b(qk[((t * 2 + 1) * Hq + h) * 64 + x]);   // column read, coalesced
      vb[j] = f2b(v[(t * Hq + h) * 64 + x]);
    }
    *(short8*)&ktS[swz(x, s0)] = kb;
    *(short8*)&vtS[swz(x, s0)] = vb;
  }
  __syncthreads();

  const int w = tid >> 6, lane = tid & 63, g = lane >> 4, r16 = lane & 15;
  short8 vf[2];
#pragma unroll
  for (int kk = 0; kk < 2; ++kk)
    vf[kk] = *(const short8*)&vtS[swz(16 * w + r16, kk * 32 + 8 * g)];

  ushort_t* dst = kvw + (((size_t)((b * Hq + h) * NC + c)) << 12);
#pragma unroll
  for (int j = 0; j < 4; ++j) {
    f32x4 acc = {0.f, 0.f, 0.f, 0.f};
#pragma unroll
    for (int kk = 0; kk < 2; ++kk) {
      short8 kf = *(const short8*)&ktS[swz(16 * j + r16, kk * 32 + 8 * g)];
      acc = __builtin_amdgcn_mfma_f32_16x16x32_bf16(vf[kk], kf, acc, 0, 0, 0);
    }
#pragma unroll
    for (int reg = 0; reg < 4; ++reg)
      dst[(16 * w + 4 * g + reg) * 64 + 16 * j + r16] = (ushort_t)f2b(acc[reg]);
  }
}

// ---------------------------------------------------------------------------
// Kernel B: exclusive prefix over NC chunks per (b,h), packed bf16x2, fp32 accum.
// ---------------------------------------------------------------------------
__global__ __launch_bounds__(256) void kv_scan_kernel(uint_t* __restrict__ kvw) {
  const int gi = blockIdx.x * 256 + threadIdx.x;  // 65536 threads
  const int bh = gi >> 11, e = gi & 2047;
  uint_t* p = kvw + (size_t)bh * NC * 2048 + e;
  float r0 = 0.f, r1 = 0.f;
#pragma unroll
  for (int c = 0; c < NC; ++c) {
    uint_t xv = p[c * 2048];
    float lo = __uint_as_float(xv << 16);
    float hi = __uint_as_float(xv & 0xffff0000u);
    p[c * 2048] = ((uint_t)(ushort_t)f2b(r1) << 16) | (ushort_t)(ushort_t)f2b(r0);
    r0 += lo;
    r1 += hi;
  }
}

// ---------------------------------------------------------------------------
// Kernel C: O = gate * ( mask(Q K^T) V + Q M_prev ).  4 swizzled LDS buffers
// (33KB -> 4 blocks/CU); scores overwrite the Q tile after qf regs are loaded.
// ---------------------------------------------------------------------------
__global__ __launch_bounds__(256) void attn_out_kernel(
    const float* __restrict__ qk, const float* __restrict__ v,
    const float* __restrict__ nrm, const ushort_t* __restrict__ kvw,
    float* __restrict__ out) {
  const int bid = blockIdx.x;
  const int c = bid & (NC - 1), h = (bid / NC) & (Hq - 1), b = bid / (NC * Hq);
  const int t0 = c * CHUNK;
  const int tid = threadIdx.x;
  __shared__ short qS[4096];    // Q[t][d], then masked scores Sm[t][s]
  __shared__ short kS[4096];    // K[s][d]
  __shared__ short vtS[4096];   // V^T[dv][s]
  __shared__ short mtS[4096];   // M^T[dv][dk]
  __shared__ float gateS[64];

  const ushort_t* mws = kvw + (((size_t)((b * Hq + h) * NC + c)) << 12);

  {
    const int rh = tid >> 3, sl = tid & 7;   // 32 rows x 8 slots per pass
    for (int i = 0; i < 2; ++i) {
      const int rr = rh + 32 * i;
      const size_t t = (size_t)(b * Sq + t0 + rr);
      const float4* qp = (const float4*)(qk + ((t * 2 + 0) * Hq + h) * 64) + sl * 2;
      const float4* kp = (const float4*)(qk + ((t * 2 + 1) * Hq + h) * 64) + sl * 2;
      float4 q0 = qp[0], q1 = qp[1], k0 = kp[0], k1 = kp[1];
      short8 qb, kb;
      qb[0] = f2b(q0.x); qb[1] = f2b(q0.y); qb[2] = f2b(q0.z); qb[3] = f2b(q0.w);
      qb[4] = f2b(q1.x); qb[5] = f2b(q1.y); qb[6] = f2b(q1.z); qb[7] = f2b(q1.w);
      kb[0] = f2b(k0.x); kb[1] = f2b(k0.y); kb[2] = f2b(k0.z); kb[3] = f2b(k0.w);
      kb[4] = f2b(k1.x); kb[5] = f2b(k1.y); kb[6] = f2b(k1.z); kb[7] = f2b(k1.w);
      *(short8*)&qS[swz(rr, sl * 8)] = qb;
      *(short8*)&kS[swz(rr, sl * 8)] = kb;
      short8 m8 = *(const short8*)(mws + rr * 64 + sl * 8);   // bf16 passthrough
      *(short8*)&mtS[swz(rr, sl * 8)] = m8;
    }
    const int dv = tid & 63, seg = tid >> 6;
    for (int e = 0; e < 2; ++e) {
      const int s0 = seg * 16 + e * 8;
      short8 vb;
#pragma unroll
      for (int j = 0; j < 8; ++j)
        vb[j] = f2b(v[((size_t)(b * Sq + t0 + s0 + j) * Hq + h) * 64 + dv]);
      *(short8*)&vtS[swz(dv, s0)] = vb;
    }
    if (tid < 64)
      gateS[tid] = __expf(-nrm[((size_t)(b * Sq) + t0 + tid) * Hq + h]);
  }
  __syncthreads();

  const int w = tid >> 6, lane = tid & 63, g = lane >> 4, r16 = lane & 15;
  short8 qf[2];
#pragma unroll
  for (int kk = 0; kk < 2; ++kk)
    qf[kk] = *(const short8*)&qS[swz(16 * w + r16, kk * 32 + 8 * g)];
  __syncthreads();   // all qf loaded -> qS reusable as score buffer

  // S = Q K^T (tiles j<=w), causal mask at the C/D lane map, bf16 into qS.
  for (int j = 0; j <= w; ++j) {
    f32x4 acc = {0.f, 0.f, 0.f, 0.f};
#pragma unroll
    for (int kk = 0; kk < 2; ++kk) {
      short8 kf = *(const short8*)&kS[swz(16 * j + r16, kk * 32 + 8 * g)];
      acc = __builtin_amdgcn_mfma_f32_16x16x32_bf16(qf[kk], kf, acc, 0, 0, 0);
    }
    const int scol = 16 * j + r16;
#pragma unroll
    for (int reg = 0; reg < 4; ++reg) {
      const int trow = 16 * w + 4 * g + reg;
      qS[swz(trow, scol)] = (scol <= trow) ? f2b(acc[reg]) : (short)0;
    }
  }
  // Zero only the tiles the PV fragment reads will actually touch.
  if (w == 0 || w == 2) {
    const int scol = 16 * (w + 1) + r16;
#pragma unroll
    for (int reg = 0; reg < 4; ++reg)
      qS[swz(16 * w + 4 * g + reg, scol)] = 0;
  }
  __syncthreads();

  const int nk = (w >> 1) + 1;   // wave-uniform live s-tiles: 1,1,2,2
  short8 sf[2];
  for (int kk = 0; kk < nk; ++kk)
    sf[kk] = *(const short8*)&qS[swz(16 * w + r16, kk * 32 + 8 * g)];
  float gr[4];
#pragma unroll
  for (int reg = 0; reg < 4; ++reg) gr[reg] = gateS[16 * w + 4 * g + reg];

#pragma unroll
  for (int j = 0; j < 4; ++j) {
    f32x4 acc = {0.f, 0.f, 0.f, 0.f};
    for (int kk = 0; kk < nk; ++kk) {
      short8 vfr = *(const short8*)&vtS[swz(16 * j + r16, kk * 32 + 8 * g)];
      acc = __builtin_amdgcn_mfma_f32_16x16x32_bf16(sf[kk], vfr, acc, 0, 0, 0);
    }
#pragma unroll
    for (int kk = 0; kk < 2; ++kk) {
      short8 mfr = *(const short8*)&mtS[swz(16 * j + r16, kk * 32 + 8 * g)];
      acc = __builtin_amdgcn_mfma_f32_16x16x32_bf16(qf[kk], mfr, acc, 0, 0, 0);
    }
    const int dvv = 16 * j + r16;
#pragma unroll
    for (int reg = 0; reg < 4; ++reg) {
      const int trow = 16 * w + 4 * g + reg;
      out[((size_t)(b * Sq + t0 + trow) * Hq + h) * 64 + dvv] = gr[reg] * acc[reg];
    }
  }
}

extern "C" void kernel_launch(void* const* d_in, const int* in_sizes, int n_in,
                              void* d_out, int out_size, void* d_ws, size_t ws_size,
                              hipStream_t stream) {
  const float* qk = (const float*)d_in[0];
  const float* v  = (const float*)d_in[1];
  const float* nn = (const float*)d_in[2];
  float* out = (float*)d_out;

  kv_chunk_kernel<<<Bq * Hq * NC, 256, 0, stream>>>(qk, v, (ushort_t*)d_ws);
  kv_scan_kernel<<<256, 256, 0, stream>>>((uint_t*)d_ws);
  attn_out_kernel<<<Bq * Hq * NC, 256, 0, stream>>>(qk, v, nn,
                                                    (const ushort_t*)d_ws, out);
}